// Round 4
// baseline (33689.615 us; speedup 1.0000x reference)
//
#include <hip/hip_runtime.h>
#include <hip/hip_bf16.h>

#define TT 512
#define BB 256
#define INS 128
#define HH 256
#define SP1 129
#define NBLK 256
#define BT 16
#define HT 16
#define FLAG_STRIDE 64   // 64 uints = 256B per flag slot

__device__ __forceinline__ float sigmoidf_(float v) { return 1.0f / (1.0f + expf(-v)); }

// Cache-bypass (coherence-point) accessors for cross-block data exchange.
// Relaxed system-scope atomics compile to global_load/store with sc0 sc1 on
// gfx950 -> bypass L1/L2, coherent (and cached) at MALL.
__device__ __forceinline__ float ld_coh(const float* p) {
    return __hip_atomic_load(p, __ATOMIC_RELAXED, __HIP_MEMORY_SCOPE_SYSTEM);
}
__device__ __forceinline__ void st_coh(float* p, float v) {
    __hip_atomic_store(p, v, __ATOMIC_RELAXED, __HIP_MEMORY_SCOPE_SYSTEM);
}

// pts[t][b] = cumsum of ops[0..t][b]  (ops[0]==0)
__global__ void k_pts(const int* __restrict__ ops, int* __restrict__ pts) {
    int b = threadIdx.x;
    int acc = 0;
#pragma unroll 4
    for (int t = 0; t < TT; ++t) {
        acc += ops[t * BB + b];
        pts[t * BB + b] = acc;
    }
}

// level 0 of the stacks = h0/c0 broadcast over batch (kernel-boundary release
// flushes these to the coherence point before k_main starts)
__global__ void k_init(const float* __restrict__ h0, const float* __restrict__ c0,
                       float* __restrict__ hS, float* __restrict__ cS) {
    int i = blockIdx.x * 256 + threadIdx.x;   // i = b*HH + h, level 0
    int h = i & (HH - 1);
    hS[i] = h0[h];
    cS[i] = c0[h];
}

__global__ __launch_bounds__(256)
void k_main(const float* __restrict__ x, const int* __restrict__ ops,
            const float* __restrict__ wxi, const float* __restrict__ bi,
            const float* __restrict__ whi, const float* __restrict__ wci,
            const float* __restrict__ wxf, const float* __restrict__ bfp,
            const float* __restrict__ whf, const float* __restrict__ wcf,
            const float* __restrict__ wxc, const float* __restrict__ bcp,
            const float* __restrict__ wxo, const float* __restrict__ bop,
            const float* __restrict__ who, const float* __restrict__ wco,
            float* __restrict__ hS, float* __restrict__ cS,
            const int* __restrict__ pts, unsigned* __restrict__ flags,
            float* __restrict__ out)
{
    const int tid   = threadIdx.x;
    const int blk   = blockIdx.x;
    const int btile = blk >> 4;    // group id: 16 consecutive blocks share a btile
    const int htile = blk & 15;
    const int hl = tid & 15, bl = tid >> 4;
    const int hg = htile * HT + hl;
    const int bg = btile * BT + bl;
    const int wv = tid >> 6;       // wave 0..3
    const int ln = tid & 63;       // lane

    // +4 pad: float4-aligned rows, rows offset by 4 banks (conflict-free b128)
    __shared__ float sh[BT][HH + 4];
    __shared__ float sc[BT][HH + 4];

    const float bi_ = bi[hg], bf_ = bfp[hg], bc_ = bcp[hg], bo_ = bop[hg];
    const float* wxi_r = wxi + hg * INS;
    const float* wxf_r = wxf + hg * INS;
    const float* wxc_r = wxc + hg * INS;
    const float* wxo_r = wxo + hg * INS;
    const float* whi_r = whi + hg * HH;
    const float* whf_r = whf + hg * HH;
    const float* who_r = who + hg * HH;
    const float* wci_r = wci + hg * HH;
    const float* wcf_r = wcf + hg * HH;
    const float* wco_r = wco + hg * HH;

    unsigned* grpflags = flags + (size_t)btile * 16 * FLAG_STRIDE;

    for (int t = 0; t < TT; ++t) {
        const int tB = t * BB;

        // ---- Phase A: x-projections (no dependence on other blocks) ----
        float xa_i = bi_, xa_f = bf_, xa_c = bc_, xa_o = bo_;
        {
            const float* xrow = x + ((size_t)tB + bg) * INS;
#pragma unroll 8
            for (int k = 0; k < INS; k += 4) {
                float4 xv = *(const float4*)(xrow + k);
                float4 w;
                w = *(const float4*)(wxi_r + k); xa_i += xv.x*w.x + xv.y*w.y + xv.z*w.z + xv.w*w.w;
                w = *(const float4*)(wxf_r + k); xa_f += xv.x*w.x + xv.y*w.y + xv.z*w.z + xv.w*w.w;
                w = *(const float4*)(wxc_r + k); xa_c += xv.x*w.x + xv.y*w.y + xv.z*w.z + xv.w*w.w;
                w = *(const float4*)(wxo_r + k); xa_o += xv.x*w.x + xv.y*w.y + xv.z*w.z + xv.w*w.w;
            }
        }
        const int pt = pts[tB + bg];
        const int op = ops[(t + 1) * BB + bg];

        // ---- Phase B: wait for all 16 group members to finish step t-1 ----
        // Busy-spin with a dependent FMA chain between polls: keeps every CU's
        // VALU hot (DPM holds boost clocks) and avoids s_sleep wake latency.
        if (tid < 16) {
            unsigned* f = grpflags + tid * FLAG_STRIDE;
            const unsigned want = (unsigned)t;
            float dummy = xa_i;
            while (__hip_atomic_load(f, __ATOMIC_RELAXED, __HIP_MEMORY_SCOPE_AGENT) < want) {
#pragma unroll
                for (int z = 0; z < 32; ++z)
                    dummy = __builtin_fmaf(dummy, 0.99999988f, 1.0e-7f);
                asm volatile("" : "+v"(dummy));   // keep the chain live
            }
        }
        __syncthreads();

        // ---- Phase C: gather cur_h/cur_c via coherence point -> LDS ----
#pragma unroll
        for (int r = 0; r < 4; ++r) {
            int row = wv * 4 + r;
            int bgr = btile * BT + row;
            int ptr = pts[tB + bgr];
            size_t base = ((size_t)ptr * BB + bgr) * HH;
#pragma unroll
            for (int i = 0; i < 4; ++i) {
                int col = i * 64 + ln;
                sh[row][col] = ld_coh(hS + base + col);
                sc[row][col] = ld_coh(cS + base + col);
            }
        }
        // prev_h level (pt-1)%129 was last written >= 2 steps ago: safe to
        // prefetch here, overlaps with the compute phase
        float prev = 0.f;
        if (op <= 0) {
            int pm = (pt == 0) ? (SP1 - 1) : (pt - 1);
            prev = ld_coh(hS + ((size_t)pm * BB + bg) * HH + hg);
        }
        __syncthreads();

        // ---- Phase D: 6 dot products over K=256 (weights stay hot in L1/L2) ----
        float a_i = xa_i, a_f = xa_f, a_o = xa_o, a_hf = 0.f;
#pragma unroll 4
        for (int k = 0; k < HH; k += 4) {
            float4 hv = *(const float4*)&sh[bl][k];
            float4 cv = *(const float4*)&sc[bl][k];
            float4 w;
            w = *(const float4*)(whi_r + k); a_i  += hv.x*w.x + hv.y*w.y + hv.z*w.z + hv.w*w.w;
            w = *(const float4*)(wci_r + k); a_i  += cv.x*w.x + cv.y*w.y + cv.z*w.z + cv.w*w.w;
            w = *(const float4*)(whf_r + k); a_hf += hv.x*w.x + hv.y*w.y + hv.z*w.z + hv.w*w.w;
            w = *(const float4*)(wcf_r + k); a_f  += cv.x*w.x + cv.y*w.y + cv.z*w.z + cv.w*w.w;
            w = *(const float4*)(who_r + k); a_o  += hv.x*w.x + hv.y*w.y + hv.z*w.z + hv.w*w.w;
            w = *(const float4*)(wco_r + k); a_o  += cv.x*w.x + cv.y*w.y + cv.z*w.z + cv.w*w.w;
        }

        float ig = sigmoidf_(a_i);
        float fg = sigmoidf_(a_f + a_hf);
        float og = sigmoidf_(a_o);
        float curc = sc[bl][hg];
        float cg = fg * curc + ig * tanhf(xa_c + a_hf);  // NOTE: w_hf reuse, per ref
        float nh = og * tanhf(cg);

        // ---- Phase E: publish via coherence point, then flag ----
        size_t wix = ((size_t)(pt + 1) * BB + bg) * HH + hg;
        st_coh(hS + wix, nh);
        st_coh(cS + wix, cg);
        out[((size_t)tB + bg) * HH + hg] = (op > 0) ? nh : prev;

        asm volatile("s_waitcnt vmcnt(0)" ::: "memory");  // drain this wave's stores
        __syncthreads();                                   // all waves drained now
        if (tid == 0)
            __hip_atomic_store(grpflags + htile * FLAG_STRIDE, (unsigned)(t + 1),
                               __ATOMIC_RELAXED, __HIP_MEMORY_SCOPE_AGENT);
    }
}

extern "C" void kernel_launch(void* const* d_in, const int* in_sizes, int n_in,
                              void* d_out, int out_size, void* d_ws, size_t ws_size,
                              hipStream_t stream) {
    const float* x   = (const float*)d_in[0];
    const int*   ops = (const int*)d_in[1];
    const float* wxi = (const float*)d_in[2];
    const float* bi  = (const float*)d_in[3];
    const float* whi = (const float*)d_in[4];
    const float* wci = (const float*)d_in[5];
    const float* wxf = (const float*)d_in[6];
    const float* bf  = (const float*)d_in[7];
    const float* whf = (const float*)d_in[8];
    const float* wcf = (const float*)d_in[9];
    const float* wxc = (const float*)d_in[10];
    const float* bc  = (const float*)d_in[11];
    const float* wxo = (const float*)d_in[12];
    const float* bo  = (const float*)d_in[13];
    const float* who = (const float*)d_in[14];
    const float* wco = (const float*)d_in[15];
    const float* h0  = (const float*)d_in[16];
    const float* c0  = (const float*)d_in[17];
    float* out = (float*)d_out;

    const size_t stackElems = (size_t)SP1 * BB * HH;  // 8,454,144 floats per stack
    const size_t flagElems  = (size_t)256 * FLAG_STRIDE;
    float*    hS    = (float*)d_ws;
    float*    cS    = hS + stackElems;
    int*      pts   = (int*)(cS + stackElems);
    unsigned* flags = (unsigned*)(pts + (size_t)TT * BB);
    size_t need = (size_t)((char*)(flags + flagElems) - (char*)d_ws);
    if (ws_size < need) return;

    // stacks must start as zeros (level 128 IS read as zeros when pt==0)
    hipMemsetAsync(d_ws, 0, stackElems * 2 * sizeof(float), stream);
    hipMemsetAsync((void*)flags, 0, flagElems * sizeof(unsigned), stream);
    k_pts<<<1, 256, 0, stream>>>(ops, pts);
    k_init<<<(BB * HH) / 256, 256, 0, stream>>>(h0, c0, hS, cS);
    k_main<<<NBLK, 256, 0, stream>>>(x, ops, wxi, bi, whi, wci, wxf, bf, whf, wcf,
                                     wxc, bc, wxo, bo, who, wco,
                                     hS, cS, pts, flags, out);
}